// Round 1
// baseline (1467.331 us; speedup 1.0000x reference)
//
#include <hip/hip_runtime.h>
#include <math.h>

#define NPTS 1024
#define BB 2
#define KNN 20
#define ROWS (BB*NPTS)   // 2048
#define CATC 960
#define TT 3

__device__ __forceinline__ float lrelu_f(float x){ return x >= 0.f ? x : 0.2f*x; }

// x (B,3,N) -> f0 (B,N,3)
__global__ void k_transpose(const float* __restrict__ x, float* __restrict__ f0){
  int i = blockIdx.x*256 + threadIdx.x;
  if (i >= BB*NPTS*3) return;
  int b = i / (NPTS*3);
  int rem = i - b*NPTS*3;
  int n = rem / 3, c = rem - n*3;
  f0[i] = x[(size_t)b*3*NPTS + (size_t)c*NPTS + n];
}

// Wcat (2O x C) from W (O x 2C): rows [0,O) = Wlo+Whi, rows [O,2O) = Wlo
__global__ void k_wcat(const float* __restrict__ W, float* __restrict__ Wcat, int O, int C){
  int i = blockIdx.x*256 + threadIdx.x;
  if (i >= 2*O*C) return;
  int r = i / C, c = i - r*C;
  if (r < O) Wcat[i] = W[(size_t)r*2*C + c] + W[(size_t)r*2*C + C + c];
  else       Wcat[i] = W[(size_t)(r-O)*2*C + c];
}

// per-row sum of squares, serial exact order (binary rows exact; C=3 matches ref order)
__global__ void k_rowsq(const float* __restrict__ f, int ld, int C, float* __restrict__ x2){
  int r = blockIdx.x*256 + threadIdx.x;
  if (r >= ROWS) return;
  const float* p = f + (size_t)r*ld;
  float s = 0.f;
  for (int c = 0; c < C; ++c) s = __fadd_rn(s, __fmul_rn(p[c], p[c]));
  x2[r] = s;
}

// layer-0 neg distance, exact op-order match with reference (C=3)
__global__ void k_negd3(const float* __restrict__ f0, const float* __restrict__ x2,
                        float* __restrict__ negd){
  int m = blockIdx.x*256 + threadIdx.x;
  if (m >= NPTS) return;
  int n = blockIdx.y, b = blockIdx.z;
  const float* fn = f0 + ((size_t)b*NPTS + n)*3;
  const float* fm = f0 + ((size_t)b*NPTS + m)*3;
  float inner = __fadd_rn(__fadd_rn(__fmul_rn(fn[0],fm[0]), __fmul_rn(fn[1],fm[1])),
                          __fmul_rn(fn[2],fm[2]));
  float v = __fsub_rn(__fsub_rn(__fmul_rn(2.f, inner), x2[b*NPTS+n]), x2[b*NPTS+m]);
  negd[((size_t)b*NPTS + n)*NPTS + m] = v;
}

// generic NT SGEMM 64x64 tile: C[m][n] = sum_k A[m][k]*B[n][k]
// mode 0: plain store. mode 1: store 2*acc - x2A[m] - x2B[n] (neg distance)
__global__ __launch_bounds__(256)
void k_sgemm(const float* __restrict__ A, int lda, size_t sAz,
             const float* __restrict__ Bm, int ldb, size_t sBz,
             float* __restrict__ C, int ldc, size_t sCz,
             int K, int mode,
             const float* __restrict__ x2A, const float* __restrict__ x2B, size_t sX2z)
{
  __shared__ float As[64][17];
  __shared__ float Bs[64][17];
  int z = blockIdx.z;
  const float* Ab = A + (size_t)z*sAz;
  const float* Bb = Bm + (size_t)z*sBz;
  float* Cb = C + (size_t)z*sCz;
  int bm = blockIdx.x*64, bn = blockIdx.y*64;
  int tid = threadIdx.x;
  int tx = tid & 15, ty = tid >> 4;
  float acc[4][4] = {};
  for (int k0 = 0; k0 < K; k0 += 16) {
    for (int i = tid; i < 1024; i += 256) {
      int r = i >> 4, c = i & 15;
      int gk = k0 + c;
      As[r][c] = (gk < K) ? Ab[(size_t)(bm+r)*lda + gk] : 0.f;
      Bs[r][c] = (gk < K) ? Bb[(size_t)(bn+r)*ldb + gk] : 0.f;
    }
    __syncthreads();
#pragma unroll
    for (int kk = 0; kk < 16; ++kk) {
      float a[4], b[4];
#pragma unroll
      for (int i = 0; i < 4; ++i) a[i] = As[ty*4+i][kk];
#pragma unroll
      for (int j = 0; j < 4; ++j) b[j] = Bs[tx*4+j][kk];
#pragma unroll
      for (int i = 0; i < 4; ++i)
#pragma unroll
        for (int j = 0; j < 4; ++j)
          acc[i][j] = fmaf(a[i], b[j], acc[i][j]);
    }
    __syncthreads();
  }
  if (mode == 0) {
#pragma unroll
    for (int i = 0; i < 4; ++i) {
      int row = bm + ty*4 + i;
#pragma unroll
      for (int j = 0; j < 4; ++j)
        Cb[(size_t)row*ldc + bn + tx*4 + j] = acc[i][j];
    }
  } else {
    const float* xA = x2A + (size_t)z*sX2z;
    const float* xB = x2B + (size_t)z*sX2z;
#pragma unroll
    for (int i = 0; i < 4; ++i) {
      int row = bm + ty*4 + i;
      float xa = xA[row];
#pragma unroll
      for (int j = 0; j < 4; ++j) {
        int col = bn + tx*4 + j;
        Cb[(size_t)row*ldc + col] = 2.f*acc[i][j] - xa - xB[col];
      }
    }
  }
}

// stable top-20: iterative selection, ties -> lowest index (matches lax.top_k)
__global__ void k_topk(const float* __restrict__ negd, int* __restrict__ idx){
  int n = blockIdx.x, b = blockIdx.y;
  const float* row = negd + ((size_t)b*NPTS + n)*NPTS;
  __shared__ float vals[NPTS];
  __shared__ unsigned long long red[256];
  int tid = threadIdx.x;
  for (int i = tid; i < NPTS; i += 256) vals[i] = row[i];
  __syncthreads();
  int* out = idx + ((size_t)b*NPTS + n)*KNN;
  for (int s = 0; s < KNN; ++s) {
    unsigned long long best = 0ULL;
    for (int i = tid; i < NPTS; i += 256) {
      float v = vals[i];
      unsigned u = __float_as_uint(v);
      u = (u & 0x80000000u) ? ~u : (u | 0x80000000u);
      unsigned long long key = ((unsigned long long)u << 32) | (unsigned)(NPTS - 1 - i);
      if (key > best) best = key;
    }
    red[tid] = best;
    __syncthreads();
    for (int off = 128; off > 0; off >>= 1) {
      if (tid < off) { if (red[tid+off] > red[tid]) red[tid] = red[tid+off]; }
      __syncthreads();
    }
    int wi = NPTS - 1 - (int)(red[0] & 0xFFFFFFFFu);
    if (tid == 0) { out[s] = wi; vals[wi] = -INFINITY; }
    __syncthreads();
  }
}

// gather neighbors, per-(b,n,o) max_k, per-channel sum / sumsq (fp64 atomics)
// h_pre[b,n,k,o] = A[b,idx_k,o] - Bc[b,n,o];  AB row = [A(0..O) | Bc(O..2O)]
__global__ void k_gather(const float* __restrict__ AB, int O,
                         const int* __restrict__ idx,
                         float* __restrict__ hmax,
                         double* __restrict__ S1, double* __restrict__ S2)
{
  int base = blockIdx.x * 8;                  // 8 rows per block
  __shared__ int sidx[8*KNN];
  for (int i = threadIdx.x; i < 8*KNN; i += blockDim.x)
    sidx[i] = idx[(size_t)base*KNN + i];
  __syncthreads();
  int twoO = 2*O;
  for (int o = threadIdx.x; o < O; o += blockDim.x) {
    double ts1 = 0.0, ts2 = 0.0;
    for (int r = 0; r < 8; ++r) {
      int bn = base + r;
      int b = bn >> 10;                       // /NPTS
      float bc = AB[(size_t)bn*twoO + O + o];
      float mx = -INFINITY;
      double s1 = 0.0, s2 = 0.0;
#pragma unroll
      for (int k = 0; k < KNN; ++k) {
        int m = sidx[r*KNN + k];
        float a = AB[((size_t)(b*NPTS + m))*twoO + o];
        mx = fmaxf(mx, a);
        s1 += (double)a;
        s2 += (double)a * (double)a;
      }
      hmax[(size_t)bn*O + o] = mx - bc;
      ts1 += s1 - (double)KNN * (double)bc;
      ts2 += s2 - 2.0*(double)bc*s1 + (double)KNN*(double)bc*(double)bc;
    }
    atomicAdd(&S1[o], ts1);
    atomicAdd(&S2[o], ts2);
  }
}

__global__ void k_bnfin(const double* __restrict__ S1, const double* __restrict__ S2,
                        float* __restrict__ meaninv, int O){
  int o = blockIdx.x*256 + threadIdx.x;
  if (o >= O) return;
  double cnt = (double)ROWS * (double)KNN;
  double mean = S1[o] / cnt;
  double var  = S2[o] / cnt - mean*mean;
  meaninv[o]     = (float)mean;
  meaninv[O + o] = 1.f / sqrtf((float)var + 1e-5f);
}

// BN affine + lrelu + LIF state update; writes binary spike into scat slice
__global__ void k_bnlif(const float* __restrict__ hmax, int O,
                        const float* __restrict__ meaninv,
                        const float* __restrict__ g, const float* __restrict__ bbias,
                        const float* __restrict__ pmd, const float* __restrict__ pta,
                        const float* __restrict__ prd, const float* __restrict__ ptb,
                        float* __restrict__ mem, float* __restrict__ thr, float* __restrict__ ref,
                        float* __restrict__ sout, int offOut, int init)
{
  int i = blockIdx.x*256 + threadIdx.x;
  if (i >= ROWS*O) return;
  int bn = i / O;
  int o  = i - bn*O;
  float h = hmax[i];
  h = ((h - meaninv[o]) * meaninv[O + o]) * g[o] + bbias[o];
  h = lrelu_f(h);
  float md = fminf(fmaxf(pmd[o], 0.1f), 0.99f);
  float ta = fminf(fmaxf(pta[o], 0.001f), 0.1f);
  float rd = fminf(fmaxf(prd[o], 0.1f), 0.95f);
  float tb = ptb[o];
  float M, T, R;
  if (init) { M = 0.f; T = tb; R = 0.f; }
  else      { M = mem[i]; T = thr[i]; R = ref[i]; }
  float xv = (R <= 0.f) ? h : 0.f;
  M = M * md * (1.f - R) + xv;
  float sp = (M - T > 0.f) ? 1.f : 0.f;
  M = M * (1.f - sp);
  R = R * rd + sp;
  T = tb + (T + ta*sp - tb) * 0.95f;
  mem[i] = M; thr[i] = T; ref[i] = R;
  sout[(size_t)bn*CATC + offOut + o] = sp;
}

// aggregator: per-channel mean/var over (b,n) + per-(b) max over n, finalize pooled
__global__ void k_aggfin(const float* __restrict__ aggpre,
                         const float* __restrict__ gm, const float* __restrict__ bm,
                         float* __restrict__ pooled /* (2,512) for this t */)
{
  int o = blockIdx.x;          // 512
  int tid = threadIdx.x;       // 256
  __shared__ double sd1[256], sd2[256];
  __shared__ float sm0[256], sm1[256];
  double s1 = 0.0, s2 = 0.0;
  float m0 = -INFINITY, m1 = -INFINITY;
  for (int r = tid; r < ROWS; r += 256) {
    float v = aggpre[(size_t)r*512 + o];
    s1 += (double)v; s2 += (double)v*(double)v;
    if (r < NPTS) m0 = fmaxf(m0, v); else m1 = fmaxf(m1, v);
  }
  sd1[tid]=s1; sd2[tid]=s2; sm0[tid]=m0; sm1[tid]=m1;
  __syncthreads();
  for (int off = 128; off > 0; off >>= 1) {
    if (tid < off) {
      sd1[tid]+=sd1[tid+off]; sd2[tid]+=sd2[tid+off];
      sm0[tid]=fmaxf(sm0[tid],sm0[tid+off]);
      sm1[tid]=fmaxf(sm1[tid],sm1[tid+off]);
    }
    __syncthreads();
  }
  if (tid == 0) {
    double mean = sd1[0]/(double)ROWS;
    float var = (float)(sd2[0]/(double)ROWS - mean*mean);
    float m = (float)mean;
    float inv = 1.f/sqrtf(var + 1e-5f);
    pooled[o]       = lrelu_f(((sm0[0]-m)*inv)*gm[o] + bm[o]);
    pooled[512 + o] = lrelu_f(((sm1[0]-m)*inv)*gm[o] + bm[o]);
  }
}

// out[b,o] = ( sum_t softmax(tw)_t * pooled[t,b,o] - lftb[o] > 0 )
__global__ void k_final(const float* __restrict__ pooled, const float* __restrict__ tw,
                        const float* __restrict__ lftb, float* __restrict__ out){
  int i = blockIdx.x*256 + threadIdx.x;
  if (i >= BB*512) return;
  int b = i / 512, o = i - b*512;
  float t0 = tw[0], t1 = tw[1], t2 = tw[2];
  float mx = fmaxf(t0, fmaxf(t1, t2));
  float e0 = expf(t0-mx), e1 = expf(t1-mx), e2 = expf(t2-mx);
  float den = e0 + e1 + e2;
  float v = (e0/den)*pooled[(0*BB+b)*512+o]
          + (e1/den)*pooled[(1*BB+b)*512+o]
          + (e2/den)*pooled[(2*BB+b)*512+o];
  out[i] = (v - lftb[o] > 0.f) ? 1.f : 0.f;
}

extern "C" void kernel_launch(void* const* d_in, const int* in_sizes, int n_in,
                              void* d_out, int out_size, void* d_ws, size_t ws_size,
                              hipStream_t stream)
{
  (void)in_sizes; (void)n_in; (void)out_size; (void)ws_size;
  const float* x = (const float*)d_in[0];
  const float* Wl[4] = {(const float*)d_in[1],(const float*)d_in[4],(const float*)d_in[7],(const float*)d_in[10]};
  const float* gl[4] = {(const float*)d_in[2],(const float*)d_in[5],(const float*)d_in[8],(const float*)d_in[11]};
  const float* bl[4] = {(const float*)d_in[3],(const float*)d_in[6],(const float*)d_in[9],(const float*)d_in[12]};
  const float* Wm = (const float*)d_in[13];
  const float* gm = (const float*)d_in[14];
  const float* bm = (const float*)d_in[15];
  const float* lp[5][4];
  for (int l = 0; l < 5; ++l)
    for (int q = 0; q < 4; ++q)
      lp[l][q] = (const float*)d_in[16 + l*4 + q];
  const float* tw = (const float*)d_in[36];

  // ---- workspace carve ----
  char* pw = (char*)d_ws;
  auto alloc = [&](size_t bytes)->char* {
    char* r = pw; pw += (bytes + 255) & ~(size_t)255; return r;
  };
  float* f0     = (float*)alloc((size_t)ROWS*3*sizeof(float));
  float* x2     = (float*)alloc((size_t)ROWS*sizeof(float));
  float* negd   = (float*)alloc((size_t)BB*NPTS*NPTS*sizeof(float));
  int*   idx    = (int*)  alloc((size_t)ROWS*KNN*sizeof(int));
  float* AB     = (float*)alloc((size_t)ROWS*1024*sizeof(float));
  float* hmax0  = (float*)alloc((size_t)ROWS*64*sizeof(float));
  float* hmaxS  = (float*)alloc((size_t)ROWS*512*sizeof(float));
  float* scat   = (float*)alloc((size_t)ROWS*CATC*sizeof(float));
  float* aggpre = (float*)alloc((size_t)ROWS*512*sizeof(float));
  double* S12   = (double*)alloc(1024*sizeof(double));
  float* meaninv= (float*)alloc(4*1024*sizeof(float));
  float* pooled = (float*)alloc((size_t)TT*BB*512*sizeof(float));

  int Cin[4]   = {3, 64, 128, 256};
  int Oo[4]    = {64, 128, 256, 512};
  int offIn[4] = {0, 0, 64, 192};
  int offOut[4]= {0, 64, 192, 448};
  float *wcat[4], *stM[4], *stT[4], *stR[4];
  for (int i = 0; i < 4; ++i) {
    wcat[i] = (float*)alloc((size_t)2*Oo[i]*Cin[i]*sizeof(float));
    stM[i]  = (float*)alloc((size_t)ROWS*Oo[i]*sizeof(float));
    stT[i]  = (float*)alloc((size_t)ROWS*Oo[i]*sizeof(float));
    stR[i]  = (float*)alloc((size_t)ROWS*Oo[i]*sizeof(float));
  }
  double* S1 = S12; double* S2 = S12 + 512;

  // ---- setup (time-invariant) ----
  k_transpose<<<(BB*NPTS*3+255)/256, 256, 0, stream>>>(x, f0);
  for (int i = 0; i < 4; ++i)
    k_wcat<<<(2*Oo[i]*Cin[i]+255)/256, 256, 0, stream>>>(Wl[i], wcat[i], Oo[i], Cin[i]);
  // layer-0 KNN + conv-max + BN stats (same at every t)
  k_rowsq<<<(ROWS+255)/256, 256, 0, stream>>>(f0, 3, 3, x2);
  k_negd3<<<dim3(4, NPTS, BB), 256, 0, stream>>>(f0, x2, negd);
  k_topk<<<dim3(NPTS, BB), 256, 0, stream>>>(negd, idx);
  k_sgemm<<<dim3(ROWS/64, (2*Oo[0])/64, 1), 256, 0, stream>>>(
      f0, 3, 0, wcat[0], 3, 0, AB, 2*Oo[0], 0, 3, 0, nullptr, nullptr, 0);
  hipMemsetAsync(S12, 0, 1024*sizeof(double), stream);
  k_gather<<<ROWS/8, 256, 0, stream>>>(AB, Oo[0], idx, hmax0, S1, S2);
  k_bnfin<<<1, 256, 0, stream>>>(S1, S2, meaninv, Oo[0]);

  // ---- time steps ----
  for (int t = 0; t < TT; ++t) {
    int init = (t == 0) ? 1 : 0;
    // layer 0: only LIF evolves
    k_bnlif<<<(ROWS*Oo[0]+255)/256, 256, 0, stream>>>(
        hmax0, Oo[0], meaninv, gl[0], bl[0],
        lp[0][0], lp[0][1], lp[0][2], lp[0][3],
        stM[0], stT[0], stR[0], scat, offOut[0], init);
    for (int i = 1; i < 4; ++i) {
      int C = Cin[i], O = Oo[i];
      const float* fin = scat + offIn[i];
      k_rowsq<<<(ROWS+255)/256, 256, 0, stream>>>(fin, CATC, C, x2);
      k_sgemm<<<dim3(NPTS/64, NPTS/64, BB), 256, 0, stream>>>(
          fin, CATC, (size_t)NPTS*CATC, fin, CATC, (size_t)NPTS*CATC,
          negd, NPTS, (size_t)NPTS*NPTS, C, 1, x2, x2, NPTS);
      k_topk<<<dim3(NPTS, BB), 256, 0, stream>>>(negd, idx);
      k_sgemm<<<dim3(ROWS/64, (2*O)/64, 1), 256, 0, stream>>>(
          fin, CATC, 0, wcat[i], C, 0, AB, 2*O, 0, C, 0, nullptr, nullptr, 0);
      hipMemsetAsync(S12, 0, 1024*sizeof(double), stream);
      k_gather<<<ROWS/8, 256, 0, stream>>>(AB, O, idx, hmaxS, S1, S2);
      k_bnfin<<<(O+255)/256, 256, 0, stream>>>(S1, S2, meaninv + i*1024, O);
      k_bnlif<<<(ROWS*O+255)/256, 256, 0, stream>>>(
          hmaxS, O, meaninv + i*1024, gl[i], bl[i],
          lp[i][0], lp[i][1], lp[i][2], lp[i][3],
          stM[i], stT[i], stR[i], scat, offOut[i], init);
    }
    // aggregator
    k_sgemm<<<dim3(ROWS/64, 512/64, 1), 256, 0, stream>>>(
        scat, CATC, 0, Wm, CATC, 0, aggpre, 512, 0, CATC, 0, nullptr, nullptr, 0);
    k_aggfin<<<512, 256, 0, stream>>>(aggpre, gm, bm, pooled + (size_t)t*BB*512);
  }
  k_final<<<(BB*512+255)/256, 256, 0, stream>>>(pooled, tw, lp[4][3], (float*)d_out);
}

// Round 2
// 716.208 us; speedup vs baseline: 2.0487x; 2.0487x over previous
//
#include <hip/hip_runtime.h>
#include <math.h>

#define NPTS 1024
#define BB 2
#define KNN 20
#define ROWS (BB*NPTS)   // 2048
#define CATC 960
#define TT 3

__device__ __forceinline__ float lrelu_f(float x){ return x >= 0.f ? x : 0.2f*x; }

// x (B,3,N) -> f0 (B,N,3)
__global__ void k_transpose(const float* __restrict__ x, float* __restrict__ f0){
  int i = blockIdx.x*256 + threadIdx.x;
  if (i >= BB*NPTS*3) return;
  int b = i / (NPTS*3);
  int rem = i - b*NPTS*3;
  int n = rem / 3, c = rem - n*3;
  f0[i] = x[(size_t)b*3*NPTS + (size_t)c*NPTS + n];
}

// Wcat (2O x C) from W (O x 2C): rows [0,O) = Wlo+Whi, rows [O,2O) = Wlo
__global__ void k_wcat(const float* __restrict__ W, float* __restrict__ Wcat, int O, int C){
  int i = blockIdx.x*256 + threadIdx.x;
  if (i >= 2*O*C) return;
  int r = i / C, c = i - r*C;
  if (r < O) Wcat[i] = W[(size_t)r*2*C + c] + W[(size_t)r*2*C + C + c];
  else       Wcat[i] = W[(size_t)(r-O)*2*C + c];
}

// per-row sum of squares (layer-0 coords only, exact op order)
__global__ void k_rowsq(const float* __restrict__ f, int ld, int C, float* __restrict__ x2){
  int r = blockIdx.x*256 + threadIdx.x;
  if (r >= ROWS) return;
  const float* p = f + (size_t)r*ld;
  float s = 0.f;
  for (int c = 0; c < C; ++c) s = __fadd_rn(s, __fmul_rn(p[c], p[c]));
  x2[r] = s;
}

// layer-0 neg distance, exact op-order match with reference (C=3)
__global__ void k_negd3(const float* __restrict__ f0, const float* __restrict__ x2,
                        float* __restrict__ negd){
  int m = blockIdx.x*256 + threadIdx.x;
  if (m >= NPTS) return;
  int n = blockIdx.y, b = blockIdx.z;
  const float* fn = f0 + ((size_t)b*NPTS + n)*3;
  const float* fm = f0 + ((size_t)b*NPTS + m)*3;
  float inner = __fadd_rn(__fadd_rn(__fmul_rn(fn[0],fm[0]), __fmul_rn(fn[1],fm[1])),
                          __fmul_rn(fn[2],fm[2]));
  float v = __fsub_rn(__fsub_rn(__fmul_rn(2.f, inner), x2[b*NPTS+n]), x2[b*NPTS+m]);
  negd[((size_t)b*NPTS + n)*NPTS + m] = v;
}

// stable top-20 over fp32 row (layer-0 only); ties -> lowest index
__global__ void k_topk(const float* __restrict__ negd, int* __restrict__ idx){
  int n = blockIdx.x, b = blockIdx.y;
  const float* row = negd + ((size_t)b*NPTS + n)*NPTS;
  __shared__ float vals[NPTS];
  __shared__ unsigned long long red[256];
  int tid = threadIdx.x;
  for (int i = tid; i < NPTS; i += 256) vals[i] = row[i];
  __syncthreads();
  int* out = idx + ((size_t)b*NPTS + n)*KNN;
  for (int s = 0; s < KNN; ++s) {
    unsigned long long best = 0ULL;
    for (int i = tid; i < NPTS; i += 256) {
      float v = vals[i];
      unsigned u = __float_as_uint(v);
      u = (u & 0x80000000u) ? ~u : (u | 0x80000000u);
      unsigned long long key = ((unsigned long long)u << 32) | (unsigned)(NPTS - 1 - i);
      if (key > best) best = key;
    }
    red[tid] = best;
    __syncthreads();
    for (int off = 128; off > 0; off >>= 1) {
      if (tid < off) { if (red[tid+off] > red[tid]) red[tid] = red[tid+off]; }
      __syncthreads();
    }
    int wi = NPTS - 1 - (int)(red[0] & 0xFFFFFFFFu);
    if (tid == 0) { out[s] = wi; vals[wi] = -INFINITY; }
    __syncthreads();
  }
}

// fused popcount-KNN: exact integer distances + stable top-20.
// block (n, b); also block(0,0) zeroes S12 (1024 doubles) for the following gather.
template<int W>
__global__ __launch_bounds__(256)
void k_knn(const unsigned long long* __restrict__ pk, int* __restrict__ idx,
           double* __restrict__ S12)
{
  const int n = blockIdx.x, b = blockIdx.y;
  const int tid = threadIdx.x;
  if (n == 0 && b == 0) {
    for (int j = tid; j < 1024; j += 256) S12[j] = 0.0;
  }
  __shared__ unsigned long long rows[W*NPTS];
  const unsigned long long* pb = pk + (size_t)b*NPTS*W;
  for (int j = tid; j < NPTS*W; j += 256) {
    int r = j / W, w = j - r*W;
    rows[w*NPTS + r] = pb[j];
  }
  __syncthreads();
  unsigned long long cw[W];
  int pn = 0;
#pragma unroll
  for (int w = 0; w < W; ++w) { cw[w] = rows[w*NPTS + n]; pn += __popcll(cw[w]); }
  unsigned keys[4];
#pragma unroll
  for (int mi = 0; mi < 4; ++mi) {
    int m = tid + mi*256;
    int inner = 0, pm = 0;
#pragma unroll
    for (int w = 0; w < W; ++w) {
      unsigned long long rm = rows[w*NPTS + m];
      inner += __popcll(rm & cw[w]);
      pm    += __popcll(rm);
    }
    int d = 2*inner - pn - pm;                       // in [-2C, 0], exact
    keys[mi] = ((unsigned)(d + 1024) << 11) | (unsigned)(NPTS - 1 - m);
  }
  __shared__ unsigned wred[4];
  __shared__ unsigned winner;
  int* out = idx + ((size_t)b*NPTS + n)*KNN;
  const int lane = tid & 63, wid = tid >> 6;
  for (int s = 0; s < KNN; ++s) {
    unsigned loc = keys[0];
    loc = keys[1] > loc ? keys[1] : loc;
    loc = keys[2] > loc ? keys[2] : loc;
    loc = keys[3] > loc ? keys[3] : loc;
#pragma unroll
    for (int off = 32; off > 0; off >>= 1) {
      unsigned o = __shfl_xor(loc, off);
      loc = o > loc ? o : loc;
    }
    if (lane == 0) wred[wid] = loc;
    __syncthreads();
    if (tid == 0) {
      unsigned wv = wred[0];
      wv = wred[1] > wv ? wred[1] : wv;
      wv = wred[2] > wv ? wred[2] : wv;
      wv = wred[3] > wv ? wred[3] : wv;
      winner = wv;
      out[s] = NPTS - 1 - (int)(wv & 0x7FFu);
    }
    __syncthreads();
    unsigned wv = winner;
#pragma unroll
    for (int mi = 0; mi < 4; ++mi) if (keys[mi] == wv) keys[mi] = 0u;
  }
}

// NT SGEMM v2: 64x64 tile, k-major LDS, float4 ds reads, prefetch pipeline.
// C[m][n] = sum_k A[m][k]*B[n][k]
__global__ __launch_bounds__(256)
void k_sgemm(const float* __restrict__ A, int lda,
             const float* __restrict__ B, int ldb,
             float* __restrict__ C, int ldc, int K)
{
  __shared__ float As[16][64];
  __shared__ float Bs[16][64];
  const int tid = threadIdx.x;
  const int bm = blockIdx.x * 64, bn = blockIdx.y * 64;
  const int tx = tid & 15, ty = tid >> 4;
  const int lr = tid >> 2, kq = tid & 3;
  float acc[4][4] = {};
  const bool vec = ((lda & 3) == 0) && ((ldb & 3) == 0) && ((K & 15) == 0);
  if (vec) {
    const float* pA = A + (size_t)(bm+lr)*lda + kq*4;
    const float* pB = B + (size_t)(bn+lr)*ldb + kq*4;
    float4 av = *(const float4*)pA;
    float4 bv = *(const float4*)pB;
    for (int k0 = 0; k0 < K; k0 += 16) {
      As[kq*4+0][lr]=av.x; As[kq*4+1][lr]=av.y; As[kq*4+2][lr]=av.z; As[kq*4+3][lr]=av.w;
      Bs[kq*4+0][lr]=bv.x; Bs[kq*4+1][lr]=bv.y; Bs[kq*4+2][lr]=bv.z; Bs[kq*4+3][lr]=bv.w;
      __syncthreads();
      if (k0 + 16 < K) {
        av = *(const float4*)(pA + k0 + 16);
        bv = *(const float4*)(pB + k0 + 16);
      }
#pragma unroll
      for (int kk = 0; kk < 16; ++kk) {
        float4 a = *(const float4*)&As[kk][ty*4];
        float4 b = *(const float4*)&Bs[kk][tx*4];
        float ar[4] = {a.x,a.y,a.z,a.w};
        float br[4] = {b.x,b.y,b.z,b.w};
#pragma unroll
        for (int i = 0; i < 4; ++i)
#pragma unroll
          for (int j = 0; j < 4; ++j)
            acc[i][j] = fmaf(ar[i], br[j], acc[i][j]);
      }
      __syncthreads();
    }
  } else {
    for (int k0 = 0; k0 < K; k0 += 16) {
#pragma unroll
      for (int e = 0; e < 4; ++e) {
        int gk = k0 + kq*4 + e;
        As[kq*4+e][lr] = (gk < K) ? A[(size_t)(bm+lr)*lda + gk] : 0.f;
        Bs[kq*4+e][lr] = (gk < K) ? B[(size_t)(bn+lr)*ldb + gk] : 0.f;
      }
      __syncthreads();
#pragma unroll
      for (int kk = 0; kk < 16; ++kk) {
        float4 a = *(const float4*)&As[kk][ty*4];
        float4 b = *(const float4*)&Bs[kk][tx*4];
        float ar[4] = {a.x,a.y,a.z,a.w};
        float br[4] = {b.x,b.y,b.z,b.w};
#pragma unroll
        for (int i = 0; i < 4; ++i)
#pragma unroll
          for (int j = 0; j < 4; ++j)
            acc[i][j] = fmaf(ar[i], br[j], acc[i][j]);
      }
      __syncthreads();
    }
  }
#pragma unroll
  for (int i = 0; i < 4; ++i) {
    float4 v; v.x = acc[i][0]; v.y = acc[i][1]; v.z = acc[i][2]; v.w = acc[i][3];
    *(float4*)&C[(size_t)(bm + ty*4 + i)*ldc + bn + tx*4] = v;
  }
}

// gather neighbors, per-(b,n,o) max_k, per-channel sum / sumsq (fp64 atomics)
__global__ void k_gather(const float* __restrict__ AB, int O,
                         const int* __restrict__ idx,
                         float* __restrict__ hmax,
                         double* __restrict__ S1, double* __restrict__ S2)
{
  int base = blockIdx.x * 8;
  __shared__ int sidx[8*KNN];
  for (int i = threadIdx.x; i < 8*KNN; i += blockDim.x)
    sidx[i] = idx[(size_t)base*KNN + i];
  __syncthreads();
  int twoO = 2*O;
  for (int o = threadIdx.x; o < O; o += blockDim.x) {
    double ts1 = 0.0, ts2 = 0.0;
    for (int r = 0; r < 8; ++r) {
      int bn = base + r;
      int b = bn >> 10;
      float bc = AB[(size_t)bn*twoO + O + o];
      float mx = -INFINITY;
      double s1 = 0.0, s2 = 0.0;
#pragma unroll
      for (int k = 0; k < KNN; ++k) {
        int m = sidx[r*KNN + k];
        float a = AB[((size_t)(b*NPTS + m))*twoO + o];
        mx = fmaxf(mx, a);
        s1 += (double)a;
        s2 += (double)a * (double)a;
      }
      hmax[(size_t)bn*O + o] = mx - bc;
      ts1 += s1 - (double)KNN * (double)bc;
      ts2 += s2 - 2.0*(double)bc*s1 + (double)KNN*(double)bc*(double)bc;
    }
    atomicAdd(&S1[o], ts1);
    atomicAdd(&S2[o], ts2);
  }
}

// BN (from raw sums) + lrelu + LIF; writes spikes into scat slice + packed bits
__global__ void k_bnlif(const float* __restrict__ hmax, int oShift,
                        const double* __restrict__ S1, const double* __restrict__ S2,
                        const float* __restrict__ g, const float* __restrict__ bbias,
                        const float* __restrict__ pmd, const float* __restrict__ pta,
                        const float* __restrict__ prd, const float* __restrict__ ptb,
                        float* __restrict__ mem, float* __restrict__ thr, float* __restrict__ ref,
                        float* __restrict__ sout, int offOut,
                        unsigned long long* __restrict__ pk, int init)
{
  int i = blockIdx.x*256 + threadIdx.x;
  int O = 1 << oShift;
  int bn = i >> oShift;
  int o  = i & (O - 1);
  double cnt = (double)ROWS * (double)KNN;
  double mu = S1[o] / cnt;
  double vv = S2[o] / cnt - mu*mu;
  float mean = (float)mu;
  float inv  = 1.f / sqrtf((float)vv + 1e-5f);
  float h = hmax[i];
  h = ((h - mean) * inv) * g[o] + bbias[o];
  h = lrelu_f(h);
  float md = fminf(fmaxf(pmd[o], 0.1f), 0.99f);
  float ta = fminf(fmaxf(pta[o], 0.001f), 0.1f);
  float rd = fminf(fmaxf(prd[o], 0.1f), 0.95f);
  float tb = ptb[o];
  float M, T, R;
  if (init) { M = 0.f; T = tb; R = 0.f; }
  else      { M = mem[i]; T = thr[i]; R = ref[i]; }
  float xv = (R <= 0.f) ? h : 0.f;
  M = M * md * (1.f - R) + xv;
  float sp = (M - T > 0.f) ? 1.f : 0.f;
  M = M * (1.f - sp);
  R = R * rd + sp;
  T = tb + (T + ta*sp - tb) * 0.95f;
  mem[i] = M; thr[i] = T; ref[i] = R;
  sout[(size_t)bn*CATC + offOut + o] = sp;
  unsigned long long ball = __ballot(sp != 0.f);
  if ((threadIdx.x & 63) == 0) pk[i >> 6] = ball;
}

// aggregator: per-channel mean/var over (b,n) + per-b max over n, finalize pooled
__global__ void k_aggfin(const float* __restrict__ aggpre,
                         const float* __restrict__ gm, const float* __restrict__ bm,
                         float* __restrict__ pooled)
{
  int o = blockIdx.x;
  int tid = threadIdx.x;
  __shared__ double sd1[256], sd2[256];
  __shared__ float sm0[256], sm1[256];
  double s1 = 0.0, s2 = 0.0;
  float m0 = -INFINITY, m1 = -INFINITY;
  for (int r = tid; r < ROWS; r += 256) {
    float v = aggpre[(size_t)r*512 + o];
    s1 += (double)v; s2 += (double)v*(double)v;
    if (r < NPTS) m0 = fmaxf(m0, v); else m1 = fmaxf(m1, v);
  }
  sd1[tid]=s1; sd2[tid]=s2; sm0[tid]=m0; sm1[tid]=m1;
  __syncthreads();
  for (int off = 128; off > 0; off >>= 1) {
    if (tid < off) {
      sd1[tid]+=sd1[tid+off]; sd2[tid]+=sd2[tid+off];
      sm0[tid]=fmaxf(sm0[tid],sm0[tid+off]);
      sm1[tid]=fmaxf(sm1[tid],sm1[tid+off]);
    }
    __syncthreads();
  }
  if (tid == 0) {
    double mean = sd1[0]/(double)ROWS;
    float var = (float)(sd2[0]/(double)ROWS - mean*mean);
    float m = (float)mean;
    float inv = 1.f/sqrtf(var + 1e-5f);
    pooled[o]       = lrelu_f(((sm0[0]-m)*inv)*gm[o] + bm[o]);
    pooled[512 + o] = lrelu_f(((sm1[0]-m)*inv)*gm[o] + bm[o]);
  }
}

__global__ void k_final(const float* __restrict__ pooled, const float* __restrict__ tw,
                        const float* __restrict__ lftb, float* __restrict__ out){
  int i = blockIdx.x*256 + threadIdx.x;
  if (i >= BB*512) return;
  int b = i / 512, o = i - b*512;
  float t0 = tw[0], t1 = tw[1], t2 = tw[2];
  float mx = fmaxf(t0, fmaxf(t1, t2));
  float e0 = expf(t0-mx), e1 = expf(t1-mx), e2 = expf(t2-mx);
  float den = e0 + e1 + e2;
  float v = (e0/den)*pooled[(0*BB+b)*512+o]
          + (e1/den)*pooled[(1*BB+b)*512+o]
          + (e2/den)*pooled[(2*BB+b)*512+o];
  out[i] = (v - lftb[o] > 0.f) ? 1.f : 0.f;
}

extern "C" void kernel_launch(void* const* d_in, const int* in_sizes, int n_in,
                              void* d_out, int out_size, void* d_ws, size_t ws_size,
                              hipStream_t stream)
{
  (void)in_sizes; (void)n_in; (void)out_size; (void)ws_size;
  const float* x = (const float*)d_in[0];
  const float* Wl[4] = {(const float*)d_in[1],(const float*)d_in[4],(const float*)d_in[7],(const float*)d_in[10]};
  const float* gl[4] = {(const float*)d_in[2],(const float*)d_in[5],(const float*)d_in[8],(const float*)d_in[11]};
  const float* bl[4] = {(const float*)d_in[3],(const float*)d_in[6],(const float*)d_in[9],(const float*)d_in[12]};
  const float* Wm = (const float*)d_in[13];
  const float* gm = (const float*)d_in[14];
  const float* bm = (const float*)d_in[15];
  const float* lp[5][4];
  for (int l = 0; l < 5; ++l)
    for (int q = 0; q < 4; ++q)
      lp[l][q] = (const float*)d_in[16 + l*4 + q];
  const float* tw = (const float*)d_in[36];

  // ---- workspace carve ----
  char* pw = (char*)d_ws;
  auto alloc = [&](size_t bytes)->char* {
    char* r = pw; pw += (bytes + 255) & ~(size_t)255; return r;
  };
  float* f0     = (float*)alloc((size_t)ROWS*3*sizeof(float));
  float* x2     = (float*)alloc((size_t)ROWS*sizeof(float));
  float* negd   = (float*)alloc((size_t)BB*NPTS*NPTS*sizeof(float));
  int*   idx0   = (int*)  alloc((size_t)ROWS*KNN*sizeof(int));
  int*   idxS   = (int*)  alloc((size_t)ROWS*KNN*sizeof(int));
  float* AB     = (float*)alloc((size_t)ROWS*1024*sizeof(float));
  float* hmax0  = (float*)alloc((size_t)ROWS*64*sizeof(float));
  float* hmaxS  = (float*)alloc((size_t)ROWS*512*sizeof(float));
  float* scat   = (float*)alloc((size_t)ROWS*CATC*sizeof(float));
  float* aggpre = (float*)alloc((size_t)ROWS*512*sizeof(float));
  double* S12_0 = (double*)alloc(1024*sizeof(double));
  double* S12   = (double*)alloc(1024*sizeof(double));
  float* pooled = (float*)alloc((size_t)TT*BB*512*sizeof(float));
  unsigned long long* pkb[4];
  int Wn[4] = {1, 2, 4, 8};   // packed words per row for layer outputs 64/128/256/512
  for (int i = 0; i < 4; ++i)
    pkb[i] = (unsigned long long*)alloc((size_t)ROWS*Wn[i]*sizeof(unsigned long long));

  int Cin[4]   = {3, 64, 128, 256};
  int Oo[4]    = {64, 128, 256, 512};
  int oSh[4]   = {6, 7, 8, 9};
  int offIn[4] = {0, 0, 64, 192};
  int offOut[4]= {0, 64, 192, 448};
  float *wcat[4], *stM[4], *stT[4], *stR[4];
  for (int i = 0; i < 4; ++i) {
    wcat[i] = (float*)alloc((size_t)2*Oo[i]*Cin[i]*sizeof(float));
    stM[i]  = (float*)alloc((size_t)ROWS*Oo[i]*sizeof(float));
    stT[i]  = (float*)alloc((size_t)ROWS*Oo[i]*sizeof(float));
    stR[i]  = (float*)alloc((size_t)ROWS*Oo[i]*sizeof(float));
  }
  double* S1_0 = S12_0; double* S2_0 = S12_0 + 512;
  double* S1 = S12;     double* S2 = S12 + 512;

  // ---- setup (time-invariant): layer-0 KNN + conv + stats ----
  k_transpose<<<(BB*NPTS*3+255)/256, 256, 0, stream>>>(x, f0);
  for (int i = 0; i < 4; ++i)
    k_wcat<<<(2*Oo[i]*Cin[i]+255)/256, 256, 0, stream>>>(Wl[i], wcat[i], Oo[i], Cin[i]);
  k_rowsq<<<(ROWS+255)/256, 256, 0, stream>>>(f0, 3, 3, x2);
  k_negd3<<<dim3(4, NPTS, BB), 256, 0, stream>>>(f0, x2, negd);
  k_topk<<<dim3(NPTS, BB), 256, 0, stream>>>(negd, idx0);
  k_sgemm<<<dim3(ROWS/64, 128/64), 256, 0, stream>>>(f0, 3, wcat[0], 3, AB, 128, 3);
  hipMemsetAsync(S12_0, 0, 1024*sizeof(double), stream);
  k_gather<<<ROWS/8, 256, 0, stream>>>(AB, 64, idx0, hmax0, S1_0, S2_0);

  // ---- time steps ----
  for (int t = 0; t < TT; ++t) {
    int init = (t == 0) ? 1 : 0;
    k_bnlif<<<(ROWS*64)/256, 256, 0, stream>>>(
        hmax0, oSh[0], S1_0, S2_0, gl[0], bl[0],
        lp[0][0], lp[0][1], lp[0][2], lp[0][3],
        stM[0], stT[0], stR[0], scat, offOut[0], pkb[0], init);
    for (int i = 1; i < 4; ++i) {
      int C = Cin[i], O = Oo[i];
      const float* fin = scat + offIn[i];
      // fused popcount KNN on previous layer's packed spikes (+ zero S12)
      switch (Wn[i-1]) {
        case 1: k_knn<1><<<dim3(NPTS, BB), 256, 0, stream>>>(pkb[i-1], idxS, S12); break;
        case 2: k_knn<2><<<dim3(NPTS, BB), 256, 0, stream>>>(pkb[i-1], idxS, S12); break;
        default: k_knn<4><<<dim3(NPTS, BB), 256, 0, stream>>>(pkb[i-1], idxS, S12); break;
      }
      k_sgemm<<<dim3(ROWS/64, (2*O)/64), 256, 0, stream>>>(
          fin, CATC, wcat[i], C, AB, 2*O, C);
      k_gather<<<ROWS/8, 256, 0, stream>>>(AB, O, idxS, hmaxS, S1, S2);
      k_bnlif<<<(ROWS*O)/256, 256, 0, stream>>>(
          hmaxS, oSh[i], S1, S2, gl[i], bl[i],
          lp[i][0], lp[i][1], lp[i][2], lp[i][3],
          stM[i], stT[i], stR[i], scat, offOut[i], pkb[i], init);
    }
    k_sgemm<<<dim3(ROWS/64, 512/64), 256, 0, stream>>>(
        scat, CATC, Wm, CATC, aggpre, 512, CATC);
    k_aggfin<<<512, 256, 0, stream>>>(aggpre, gm, bm, pooled + (size_t)t*BB*512);
  }
  k_final<<<(BB*512+255)/256, 256, 0, stream>>>(pooled, tw, lp[4][3], (float*)d_out);
}